// Round 2
// baseline (4816.480 us; speedup 1.0000x reference)
//
#include <hip/hip_runtime.h>

#define DIM 128
#define NCB 8
#define KSZ 2048
#define BATCH 16
#define TOK 2048
#define NTOK (BATCH * TOK)            // 32768 tokens
#define NELEM (BATCH * DIM * TOK)     // 4194304
#define T_TILE 64
#define KSLICE (KSZ / 4)              // 512 codes per wave (4 waves/block)

// ---------------------------------------------------------------------------
// init: residual[b*TOK+t][d] = x[b][d][t]  (tiled 32x32 transpose)
// grid: 16 * 4 * 64 = 4096 blocks, 256 threads
// ---------------------------------------------------------------------------
__global__ void rvq_init_transpose(const float* __restrict__ x,
                                   float* __restrict__ res) {
    __shared__ float tile[32][33];
    int bid = blockIdx.x;
    int tt = bid & 63; int rest = bid >> 6;
    int dd = rest & 3; int b = rest >> 2;
    int t0 = tt * 32, d0 = dd * 32;
    int tx = threadIdx.x & 31, ty = threadIdx.x >> 5;   // ty 0..7

    const float* xb = x + (size_t)b * DIM * TOK;
#pragma unroll
    for (int yy = 0; yy < 4; ++yy) {
        int d = d0 + ty * 4 + yy;
        tile[ty * 4 + yy][tx] = xb[(size_t)d * TOK + t0 + tx];
    }
    __syncthreads();
    float* rb = res + (size_t)b * TOK * DIM;
#pragma unroll
    for (int yy = 0; yy < 4; ++yy) {
        int t = t0 + ty * 4 + yy;
        rb[(size_t)t * DIM + d0 + tx] = tile[tx][ty * 4 + yy];
    }
}

// ---------------------------------------------------------------------------
// cnorm[s][k] = sum_d cb[s][k][d]^2 ; also zero loss accumulator
// ---------------------------------------------------------------------------
__global__ void rvq_cnorm(const float* __restrict__ cbs,
                          float* __restrict__ cnorm,
                          float* __restrict__ loss_acc) {
    if (blockIdx.x == 0 && threadIdx.x == 0) *loss_acc = 0.0f;
    int k = blockIdx.x * 256 + threadIdx.x;   // 0..16383
    const float4* row = (const float4*)(cbs + (size_t)k * DIM);
    float s = 0.0f;
#pragma unroll
    for (int i = 0; i < DIM / 4; ++i) {
        float4 v = row[i];
        s += v.x * v.x + v.y * v.y + v.z * v.z + v.w * v.w;
    }
    cnorm[k] = s;
}

// ---------------------------------------------------------------------------
// one RVQ stage. Each lane owns one token's residual in 128 VGPRs; the
// codebook streams through the SCALAR pipe (wave-uniform s_load), so the
// hot loop is pure v_fma(v, s, v) — no LDS, no VMEM vector traffic.
// Each of the block's 4 waves scans a 512-code K-slice for the same
// 64 tokens; argmin merged across waves in LDS.
// grid: NTOK/T_TILE = 512 blocks, 256 threads, 2 blocks/CU
// ---------------------------------------------------------------------------
__global__ __launch_bounds__(256, 2) void rvq_stage(
        const float* __restrict__ cb,      // (KSZ, DIM) this stage
        const float* __restrict__ cnorm,   // (KSZ) this stage
        float* __restrict__ residual,      // (NTOK, DIM)
        float* __restrict__ codes,         // d_out codes base + stage*TOK
        float* __restrict__ loss_acc) {
    // row stride 132 floats: 16B-aligned rows, per-lane reads land on
    // distinct-enough banks (8-way worst case, only hit twice per stage)
    __shared__ float resT[T_TILE][DIM + 4];     // 64*132*4 = 33792 B
    __shared__ float minv_s[4][T_TILE];
    __shared__ int   mini_s[4][T_TILE];
    __shared__ int   best_s[T_TILE];

    const int tid = threadIdx.x;
    const int token0 = blockIdx.x * T_TILE;
    float* resg = residual + (size_t)token0 * DIM;

    // ---- stage residual tile -> LDS [token][d] (coalesced global reads) ----
    {
        const float4* src = (const float4*)resg;
#pragma unroll
        for (int it = 0; it < 8; ++it) {
            int idx = it * 256 + tid;
            int tl = idx >> 5;              // token 0..63
            int dp = (idx & 31) << 2;       // d 0..124 step 4
            float4 v = src[idx];
            *(float4*)&resT[tl][dp] = v;
        }
    }
    __syncthreads();

    const int lane = tid & 63;
    // scalarize the wave id so codebook addresses are provably uniform
    const int wv = __builtin_amdgcn_readfirstlane(tid >> 6);   // 0..3

    // ---- my token's residual -> 128 VGPRs ----
    float r[DIM];
#pragma unroll
    for (int d4 = 0; d4 < DIM / 4; ++d4) {
        float4 v = *(const float4*)&resT[lane][d4 * 4];
        r[d4 * 4 + 0] = v.x; r[d4 * 4 + 1] = v.y;
        r[d4 * 4 + 2] = v.z; r[d4 * 4 + 3] = v.w;
    }

    // rnorm (4 partial chains)
    float n0 = 0, n1 = 0, n2 = 0, n3 = 0;
#pragma unroll
    for (int d = 0; d < DIM; d += 4) {
        n0 = fmaf(r[d + 0], r[d + 0], n0);
        n1 = fmaf(r[d + 1], r[d + 1], n1);
        n2 = fmaf(r[d + 2], r[d + 2], n2);
        n3 = fmaf(r[d + 3], r[d + 3], n3);
    }
    const float rn = (n0 + n1) + (n2 + n3);

    const float* __restrict__ cbw = cb + (size_t)wv * KSLICE * DIM;
    const float* __restrict__ cnw = cnorm + wv * KSLICE;

    float bestv = 3.4e38f; int besti = 0;
    for (int kk = 0; kk < KSLICE; ++kk) {
        const float* __restrict__ crow = cbw + kk * DIM;
        float a0 = 0, a1 = 0, a2 = 0, a3 = 0;
#pragma unroll
        for (int d = 0; d < DIM; d += 4) {
            // uniform address -> s_load_dwordx4; FMA reads one SGPR operand
            float4 c4 = *(const float4*)&crow[d];
            a0 = fmaf(r[d + 0], c4.x, a0);
            a1 = fmaf(r[d + 1], c4.y, a1);
            a2 = fmaf(r[d + 2], c4.z, a2);
            a3 = fmaf(r[d + 3], c4.w, a3);
        }
        float dot = (a0 + a1) + (a2 + a3);
        // dist = (rnorm - 2*dot) + cnorm, matching reference association
        float dist = fmaf(-2.0f, dot, rn) + cnw[kk];
        if (dist < bestv) { bestv = dist; besti = wv * KSLICE + kk; }
    }

    // ---- cross-wave argmin merge ----
    minv_s[wv][lane] = bestv;
    mini_s[wv][lane] = besti;
    __syncthreads();
    if (tid < T_TILE) {
        float bv = minv_s[0][tid]; int bi = mini_s[0][tid];
#pragma unroll
        for (int g = 1; g < 4; ++g) {
            float v = minv_s[g][tid]; int ii = mini_s[g][tid];
            if (v < bv || (v == bv && ii < bi)) { bv = v; bi = ii; }
        }
        best_s[tid] = bi;
        int b = token0 >> 11;               // token0 / TOK
        int t = (token0 & (TOK - 1)) + tid;
        codes[(size_t)b * (NCB * TOK) + t] = (float)bi;
    }
    __syncthreads();

    // ---- residual update + loss partial (coalesced) ----
    float lp = 0.0f;
    {
        float4* dst = (float4*)resg;
#pragma unroll
        for (int it = 0; it < 8; ++it) {
            int idx = it * 256 + tid;
            int tl = idx >> 5;
            int dp = (idx & 31) << 2;
            const float4 q = *(const float4*)(cb + (size_t)best_s[tl] * DIM + dp);
            float4 rv = *(const float4*)&resT[tl][dp];
            float r0 = rv.x - q.x, r1 = rv.y - q.y;
            float r2 = rv.z - q.z, r3 = rv.w - q.w;
            float4 o; o.x = r0; o.y = r1; o.z = r2; o.w = r3;
            dst[idx] = o;
            lp += r0 * r0 + r1 * r1 + r2 * r2 + r3 * r3;
        }
    }
#pragma unroll
    for (int off = 32; off > 0; off >>= 1) lp += __shfl_down(lp, off, 64);
    if (lane == 0) atomicAdd(loss_acc, lp);
}

// ---------------------------------------------------------------------------
// finalize: out0[b][d][t] = x[b][d][t] - residual[b*TOK+t][d]; write loss
// ---------------------------------------------------------------------------
__global__ void rvq_finalize(const float* __restrict__ x,
                             const float* __restrict__ res,
                             float* __restrict__ out,
                             const float* __restrict__ loss_acc,
                             float* __restrict__ loss_out) {
    __shared__ float tile[32][33];
    int bid = blockIdx.x;
    int tt = bid & 63; int rest = bid >> 6;
    int dd = rest & 3; int b = rest >> 2;
    int t0 = tt * 32, d0 = dd * 32;
    int tx = threadIdx.x & 31, ty = threadIdx.x >> 5;

    const float* rb = res + (size_t)b * TOK * DIM;
#pragma unroll
    for (int yy = 0; yy < 4; ++yy) {
        int t = t0 + ty * 4 + yy;
        tile[ty * 4 + yy][tx] = rb[(size_t)t * DIM + d0 + tx];
    }
    __syncthreads();
    const float* xb = x + (size_t)b * DIM * TOK;
    float* ob = out + (size_t)b * DIM * TOK;
#pragma unroll
    for (int yy = 0; yy < 4; ++yy) {
        int d = d0 + ty * 4 + yy;
        int t = t0 + tx;
        ob[(size_t)d * TOK + t] = xb[(size_t)d * TOK + t] - tile[tx][ty * 4 + yy];
    }
    if (bid == 0 && threadIdx.x == 0)
        *loss_out = *loss_acc * (1.0f / (float)NELEM);
}

// ---------------------------------------------------------------------------
extern "C" void kernel_launch(void* const* d_in, const int* in_sizes, int n_in,
                              void* d_out, int out_size, void* d_ws, size_t ws_size,
                              hipStream_t stream) {
    const float* x   = (const float*)d_in[0];   // (B, D, T)
    const float* cbs = (const float*)d_in[1];   // (NCB, KSZ, DIM)

    float* out      = (float*)d_out;            // (B,D,T) floats
    float* codes    = out + NELEM;              // (B,NCB,T) as float
    float* loss_out = out + NELEM + (size_t)BATCH * NCB * TOK;

    float* wsf      = (float*)d_ws;
    float* loss_acc = wsf;                       // [0]
    float* residual = wsf + 256;                 // (NTOK, DIM)
    float* cnorm    = wsf + 256 + (size_t)NTOK * DIM;  // (NCB*KSZ)

    hipLaunchKernelGGL(rvq_init_transpose, dim3(4096), dim3(256), 0, stream,
                       x, residual);
    hipLaunchKernelGGL(rvq_cnorm, dim3((NCB * KSZ) / 256), dim3(256), 0, stream,
                       cbs, cnorm, loss_acc);
    for (int cb = 0; cb < NCB; ++cb) {
        hipLaunchKernelGGL(rvq_stage, dim3(NTOK / T_TILE), dim3(256), 0, stream,
                           cbs + (size_t)cb * KSZ * DIM,
                           cnorm + (size_t)cb * KSZ,
                           residual,
                           codes + (size_t)cb * TOK,
                           loss_acc);
    }
    hipLaunchKernelGGL(rvq_finalize, dim3(4096), dim3(256), 0, stream,
                       x, residual, out, loss_acc, loss_out);
}

// Round 3
// 1417.984 us; speedup vs baseline: 3.3967x; 3.3967x over previous
//
#include <hip/hip_runtime.h>

#define DIM 128
#define NCB 8
#define KSZ 2048
#define BATCH 16
#define TOK 2048
#define NTOK (BATCH * TOK)            // 32768
#define NELEM (BATCH * DIM * TOK)     // 4194304
#define T_TILE 128                    // tokens per block
#define NCHUNK 32                     // 2048 codes / 64 per chunk

typedef float f32x4 __attribute__((ext_vector_type(4)));
typedef short s16x8 __attribute__((ext_vector_type(8)));

__device__ __forceinline__ unsigned short f2bf(float f) {
    unsigned u = __float_as_uint(f);
    u = (u + 0x7FFFu + ((u >> 16) & 1u)) >> 16;   // RNE, finite inputs only
    return (unsigned short)u;
}
__device__ __forceinline__ float bf2f(unsigned short h) {
    return __uint_as_float(((unsigned)h) << 16);
}

// ---------------------------------------------------------------------------
// prep: split codebooks into bf16 hi/lo.  2,097,152 elems / 256 = 8192 blocks
// ---------------------------------------------------------------------------
__global__ void rvq_prep_hilo(const float* __restrict__ cbs,
                              unsigned short* __restrict__ ch,
                              unsigned short* __restrict__ cl) {
    int i = blockIdx.x * 256 + threadIdx.x;
    float v = cbs[i];
    unsigned short h = f2bf(v);
    ch[i] = h;
    cl[i] = f2bf(v - bf2f(h));
}

// ---------------------------------------------------------------------------
// cnorm (exact fp32, round-1 formula) + zero loss accumulator
// ---------------------------------------------------------------------------
__global__ void rvq_cnorm(const float* __restrict__ cbs,
                          float* __restrict__ cnorm,
                          float* __restrict__ loss_acc) {
    if (blockIdx.x == 0 && threadIdx.x == 0) *loss_acc = 0.0f;
    int k = blockIdx.x * 256 + threadIdx.x;
    const float4* row = (const float4*)(cbs + (size_t)k * DIM);
    float s = 0.0f;
#pragma unroll
    for (int i = 0; i < DIM / 4; ++i) {
        float4 v = row[i];
        s += v.x * v.x + v.y * v.y + v.z * v.z + v.w * v.w;
    }
    cnorm[k] = s;
}

// ---------------------------------------------------------------------------
// fused RVQ: all 8 stages in one kernel. Block owns 128 tokens resident in
// LDS. Per stage: approx scores via 3-pass split-bf16 MFMA, per-lane top-2,
// merged top-4, exact fp32 rescore (round-1 formula), in-LDS residual update.
// grid 256 blocks (1/CU), 256 threads (4 waves, 1/SIMD).
// ---------------------------------------------------------------------------
__global__ __launch_bounds__(256, 1) void rvq_fused(
        const float* __restrict__ x,            // (B, D, T)
        const float* __restrict__ cbs,          // (NCB, KSZ, DIM) fp32
        const unsigned short* __restrict__ ch,  // bf16 hi
        const unsigned short* __restrict__ cl,  // bf16 lo
        const float* __restrict__ cng,          // (NCB*KSZ) exact cnorm
        float* __restrict__ out,                // (B, D, T)
        float* __restrict__ codes,              // (B, NCB, T) as float
        float* __restrict__ loss_acc) {
    __shared__ float res_lds[T_TILE][DIM + 4];       // 67584 B
    __shared__ unsigned short Bbuf[2][16384];        // 2 x 32768 B (dbuf)
    // merge overlay in Bbuf[0] (safe: last chunk computes from Bbuf[1])
    float* mv1 = (float*)&Bbuf[0][0];        // [128*16]
    int*   mi1 = (int*)  &Bbuf[0][4096];
    float* mv2 = (float*)&Bbuf[0][8192];
    int*   mi2 = (int*)  &Bbuf[0][12288];

    const int tid  = threadIdx.x;
    const int lane = tid & 63;
    const int wv   = __builtin_amdgcn_readfirstlane(tid >> 6);  // 0..3
    const int col16 = lane & 15;
    const int quad  = lane >> 4;

    const int token0 = blockIdx.x * T_TILE;
    const int b      = token0 >> 11;             // token0 / TOK
    const int t_in_b = token0 & (TOK - 1);

    // ---- init: x[b][d][t0..] -> res_lds[t][d] (coalesced along t) ----
    {
        const float* xb = x + (size_t)b * DIM * TOK + t_in_b;
#pragma unroll
        for (int it = 0; it < 16; ++it) {
            int idx = it * 256 + tid;            // 0..4095
            int d  = idx >> 5;
            int t4 = (idx & 31) * 4;
            float4 v = *(const float4*)(xb + (size_t)d * TOK + t4);
            res_lds[t4 + 0][d] = v.x;
            res_lds[t4 + 1][d] = v.y;
            res_lds[t4 + 2][d] = v.z;
            res_lds[t4 + 3][d] = v.w;
        }
    }
    __syncthreads();

    float my_loss = 0.0f;

#pragma unroll 1
    for (int s = 0; s < NCB; ++s) {
        const unsigned short* ch_s = ch  + (size_t)s * KSZ * DIM;
        const unsigned short* cl_s = cl  + (size_t)s * KSZ * DIM;
        const float*          cb_s = cbs + (size_t)s * KSZ * DIM;
        const float*          cn_s = cng + (size_t)s * KSZ;

        // ---- build A-fragments (hi/lo) from LDS residual ----
        // A[m=lane&15][k=quad*8+j]; wave wv owns tokens wv*32 .. +31
        s16x8 ah[2][4], al[2][4];
#pragma unroll
        for (int mt = 0; mt < 2; ++mt) {
#pragma unroll
            for (int dc = 0; dc < 4; ++dc) {
                int t  = wv * 32 + mt * 16 + col16;
                int d0 = dc * 32 + quad * 8;
                float4 u = *(const float4*)&res_lds[t][d0];
                float4 w = *(const float4*)&res_lds[t][d0 + 4];
                float e[8] = {u.x, u.y, u.z, u.w, w.x, w.y, w.z, w.w};
                s16x8 hv, lv;
#pragma unroll
                for (int j = 0; j < 8; ++j) {
                    unsigned short h = f2bf(e[j]);
                    hv[j] = (short)h;
                    lv[j] = (short)f2bf(e[j] - bf2f(h));
                }
                ah[mt][dc] = hv;
                al[mt][dc] = lv;
            }
        }

        float v1[8], v2[8]; int i1[8], i2[8];
#pragma unroll
        for (int q = 0; q < 8; ++q) {
            v1[q] = 3.4e38f; v2[q] = 3.4e38f; i1[q] = 0; i2[q] = 0;
        }

        // ---- stage chunk 0 ----
        s16x8 stg[8];
#pragma unroll
        for (int j = 0; j < 8; ++j) {
            int f = wv * 8 + j;
            int p = f >> 4, nt = (f >> 2) & 3, dc = f & 3;
            int code = nt * 16 + col16;
            int d0 = dc * 32 + quad * 8;
            const unsigned short* src = (p ? cl_s : ch_s) + (size_t)code * DIM + d0;
            stg[j] = *(const s16x8*)src;
        }
#pragma unroll
        for (int j = 0; j < 8; ++j) {
            int f = wv * 8 + j;
            *(s16x8*)&Bbuf[0][f * 512 + lane * 8] = stg[j];
        }
        __syncthreads();

        // ---- chunk loop ----
#pragma unroll 1
        for (int c = 0; c < NCHUNK; ++c) {
            const int cur = c & 1;
            if (c < NCHUNK - 1) {
                int cc = c + 1;
#pragma unroll
                for (int j = 0; j < 8; ++j) {
                    int f = wv * 8 + j;
                    int p = f >> 4, nt = (f >> 2) & 3, dc = f & 3;
                    int code = cc * 64 + nt * 16 + col16;
                    int d0 = dc * 32 + quad * 8;
                    const unsigned short* src =
                        (p ? cl_s : ch_s) + (size_t)code * DIM + d0;
                    stg[j] = *(const s16x8*)src;
                }
            }
            float cnv[4];
#pragma unroll
            for (int nt = 0; nt < 4; ++nt)
                cnv[nt] = cn_s[c * 64 + nt * 16 + col16];

            f32x4 acc[2][4];
#pragma unroll
            for (int mt = 0; mt < 2; ++mt)
#pragma unroll
                for (int nt = 0; nt < 4; ++nt)
                    acc[mt][nt] = (f32x4){0.f, 0.f, 0.f, 0.f};

#pragma unroll
            for (int dc = 0; dc < 4; ++dc) {
                s16x8 bh[4], bl[4];
#pragma unroll
                for (int nt = 0; nt < 4; ++nt) {
                    bh[nt] = *(const s16x8*)&Bbuf[cur][(nt * 4 + dc) * 512 + lane * 8];
                    bl[nt] = *(const s16x8*)&Bbuf[cur][(16 * 4 * 4 / 4 + nt * 4 + dc) * 512 + lane * 8];
                }
                // pass hh
#pragma unroll
                for (int nt = 0; nt < 4; ++nt)
#pragma unroll
                    for (int mt = 0; mt < 2; ++mt)
                        acc[mt][nt] = __builtin_amdgcn_mfma_f32_16x16x32_bf16(
                            ah[mt][dc], bh[nt], acc[mt][nt], 0, 0, 0);
                // pass lh
#pragma unroll
                for (int nt = 0; nt < 4; ++nt)
#pragma unroll
                    for (int mt = 0; mt < 2; ++mt)
                        acc[mt][nt] = __builtin_amdgcn_mfma_f32_16x16x32_bf16(
                            al[mt][dc], bh[nt], acc[mt][nt], 0, 0, 0);
                // pass hl
#pragma unroll
                for (int nt = 0; nt < 4; ++nt)
#pragma unroll
                    for (int mt = 0; mt < 2; ++mt)
                        acc[mt][nt] = __builtin_amdgcn_mfma_f32_16x16x32_bf16(
                            ah[mt][dc], bl[nt], acc[mt][nt], 0, 0, 0);
            }

            // ---- fold scores into per-lane top-2 ----
            // C/D layout: col=lane&15, row=quad*4+reg  [m89 verified]
#pragma unroll
            for (int nt = 0; nt < 4; ++nt) {
                int base = c * 64 + nt * 16 + col16;
                float cn_ = cnv[nt];
#pragma unroll
                for (int mt = 0; mt < 2; ++mt)
#pragma unroll
                    for (int r = 0; r < 4; ++r) {
                        float sc = fmaf(-2.0f, acc[mt][nt][r], cn_);
                        int slot = mt * 4 + r;
                        if (sc < v1[slot]) {
                            v2[slot] = v1[slot]; i2[slot] = i1[slot];
                            v1[slot] = sc;       i1[slot] = base;
                        } else if (sc < v2[slot]) {
                            v2[slot] = sc; i2[slot] = base;
                        }
                    }
            }

            if (c < NCHUNK - 1) {
#pragma unroll
                for (int j = 0; j < 8; ++j) {
                    int f = wv * 8 + j;
                    *(s16x8*)&Bbuf[(c + 1) & 1][f * 512 + lane * 8] = stg[j];
                }
            }
            __syncthreads();
        }

        // ---- merge per-lane top-2 into LDS ----
#pragma unroll
        for (int slot = 0; slot < 8; ++slot) {
            int mt = slot >> 2, r = slot & 3;
            int t = wv * 32 + mt * 16 + quad * 4 + r;
            mv1[t * 16 + col16] = v1[slot];
            mi1[t * 16 + col16] = i1[slot];
            mv2[t * 16 + col16] = v2[slot];
            mi2[t * 16 + col16] = i2[slot];
        }
        __syncthreads();

        // ---- per-token: top-4 select + exact fp32 rescore + update ----
        if (tid < T_TILE) {
            const int t = tid;
            float bv[4] = {3.4e38f, 3.4e38f, 3.4e38f, 3.4e38f};
            int   bi[4] = {0x7FFFFFFF, 0x7FFFFFFF, 0x7FFFFFFF, 0x7FFFFFFF};
#pragma unroll
            for (int col = 0; col < 16; ++col) {
#pragma unroll
                for (int w = 0; w < 2; ++w) {
                    float v = w ? mv2[t * 16 + col] : mv1[t * 16 + col];
                    int   i = w ? mi2[t * 16 + col] : mi1[t * 16 + col];
#pragma unroll
                    for (int j = 0; j < 4; ++j) {
                        if (v < bv[j] || (v == bv[j] && i < bi[j])) {
                            float tv = bv[j]; bv[j] = v; v = tv;
                            int   ti = bi[j]; bi[j] = i; i = ti;
                        }
                    }
                }
            }
            // exact rescore of 4 candidates (round-1 fp32 formula)
            const float* c0 = cb_s + (size_t)bi[0] * DIM;
            const float* c1 = cb_s + (size_t)bi[1] * DIM;
            const float* c2 = cb_s + (size_t)bi[2] * DIM;
            const float* c3 = cb_s + (size_t)bi[3] * DIM;
            float n0 = 0, n1 = 0, n2 = 0, n3 = 0;
            float a0[4] = {0, 0, 0, 0}, a1[4] = {0, 0, 0, 0};
            float a2[4] = {0, 0, 0, 0}, a3[4] = {0, 0, 0, 0};
#pragma unroll 8
            for (int d4 = 0; d4 < DIM / 4; ++d4) {
                float4 r4 = *(const float4*)&res_lds[t][d4 * 4];
                n0 = fmaf(r4.x, r4.x, n0); n1 = fmaf(r4.y, r4.y, n1);
                n2 = fmaf(r4.z, r4.z, n2); n3 = fmaf(r4.w, r4.w, n3);
                float4 q0 = *(const float4*)&c0[d4 * 4];
                a0[0] = fmaf(r4.x, q0.x, a0[0]); a0[1] = fmaf(r4.y, q0.y, a0[1]);
                a0[2] = fmaf(r4.z, q0.z, a0[2]); a0[3] = fmaf(r4.w, q0.w, a0[3]);
                float4 q1 = *(const float4*)&c1[d4 * 4];
                a1[0] = fmaf(r4.x, q1.x, a1[0]); a1[1] = fmaf(r4.y, q1.y, a1[1]);
                a1[2] = fmaf(r4.z, q1.z, a1[2]); a1[3] = fmaf(r4.w, q1.w, a1[3]);
                float4 q2 = *(const float4*)&c2[d4 * 4];
                a2[0] = fmaf(r4.x, q2.x, a2[0]); a2[1] = fmaf(r4.y, q2.y, a2[1]);
                a2[2] = fmaf(r4.z, q2.z, a2[2]); a2[3] = fmaf(r4.w, q2.w, a2[3]);
                float4 q3 = *(const float4*)&c3[d4 * 4];
                a3[0] = fmaf(r4.x, q3.x, a3[0]); a3[1] = fmaf(r4.y, q3.y, a3[1]);
                a3[2] = fmaf(r4.z, q3.z, a3[2]); a3[3] = fmaf(r4.w, q3.w, a3[3]);
            }
            float rn = (n0 + n1) + (n2 + n3);
            float dots[4];
            dots[0] = (a0[0] + a0[1]) + (a0[2] + a0[3]);
            dots[1] = (a1[0] + a1[1]) + (a1[2] + a1[3]);
            dots[2] = (a2[0] + a2[1]) + (a2[2] + a2[3]);
            dots[3] = (a3[0] + a3[1]) + (a3[2] + a3[3]);
            float bestd = 3.4e38f; int best = 0x7FFFFFFF;
#pragma unroll
            for (int j = 0; j < 4; ++j) {
                float dist = fmaf(-2.0f, dots[j], rn) + cn_s[bi[j]];
                if (dist < bestd || (dist == bestd && bi[j] < best)) {
                    bestd = dist; best = bi[j];
                }
            }
            codes[(size_t)b * (NCB * TOK) + (size_t)s * TOK + t_in_b + t] =
                (float)best;
            // update residual in LDS + loss partial
            const float* qb = cb_s + (size_t)best * DIM;
            float lp = 0.0f;
#pragma unroll 8
            for (int d4 = 0; d4 < DIM / 4; ++d4) {
                float4 r4 = *(const float4*)&res_lds[t][d4 * 4];
                float4 q4 = *(const float4*)&qb[d4 * 4];
                float4 nr;
                nr.x = r4.x - q4.x; nr.y = r4.y - q4.y;
                nr.z = r4.z - q4.z; nr.w = r4.w - q4.w;
                *(float4*)&res_lds[t][d4 * 4] = nr;
                lp += nr.x * nr.x + nr.y * nr.y + nr.z * nr.z + nr.w * nr.w;
            }
            my_loss += lp;
        }
        __syncthreads();
    }

    // ---- epilogue: out[b][d][t] = x - residual ----
    {
        const float* xb = x + (size_t)b * DIM * TOK + t_in_b;
        float* ob = out + (size_t)b * DIM * TOK + t_in_b;
#pragma unroll
        for (int it = 0; it < 16; ++it) {
            int idx = it * 256 + tid;
            int d  = idx >> 5;
            int t4 = (idx & 31) * 4;
            float4 v = *(const float4*)(xb + (size_t)d * TOK + t4);
            float4 o;
            o.x = v.x - res_lds[t4 + 0][d];
            o.y = v.y - res_lds[t4 + 1][d];
            o.z = v.z - res_lds[t4 + 2][d];
            o.w = v.w - res_lds[t4 + 3][d];
            *(float4*)(ob + (size_t)d * TOK + t4) = o;
        }
    }

    // ---- loss reduction (waves 2,3 contribute zeros) ----
#pragma unroll
    for (int off = 32; off > 0; off >>= 1)
        my_loss += __shfl_down(my_loss, off, 64);
    if (lane == 0) atomicAdd(loss_acc, my_loss);
}

// ---------------------------------------------------------------------------
__global__ void rvq_loss_fin(const float* __restrict__ loss_acc,
                             float* __restrict__ loss_out) {
    *loss_out = *loss_acc * (1.0f / (float)NELEM);
}

// ---------------------------------------------------------------------------
extern "C" void kernel_launch(void* const* d_in, const int* in_sizes, int n_in,
                              void* d_out, int out_size, void* d_ws, size_t ws_size,
                              hipStream_t stream) {
    const float* x   = (const float*)d_in[0];   // (B, D, T)
    const float* cbs = (const float*)d_in[1];   // (NCB, KSZ, DIM)

    float* out      = (float*)d_out;
    float* codes    = out + NELEM;
    float* loss_out = out + NELEM + (size_t)BATCH * NCB * TOK;

    float* wsf      = (float*)d_ws;
    float* loss_acc = wsf;
    unsigned short* ch = (unsigned short*)(wsf + 256);
    unsigned short* cl = ch + (size_t)NCB * KSZ * DIM;
    float* cng = (float*)(cl + (size_t)NCB * KSZ * DIM);

    hipLaunchKernelGGL(rvq_prep_hilo, dim3((NCB * KSZ * DIM) / 256), dim3(256),
                       0, stream, cbs, ch, cl);
    hipLaunchKernelGGL(rvq_cnorm, dim3((NCB * KSZ) / 256), dim3(256), 0, stream,
                       cbs, cng, loss_acc);
    hipLaunchKernelGGL(rvq_fused, dim3(NTOK / T_TILE), dim3(256), 0, stream,
                       x, cbs, ch, cl, cng, out, codes, loss_acc);
    hipLaunchKernelGGL(rvq_loss_fin, dim3(1), dim3(1), 0, stream,
                       loss_acc, loss_out);
}

// Round 4
// 548.645 us; speedup vs baseline: 8.7789x; 2.5845x over previous
//
#include <hip/hip_runtime.h>

#define DIM 128
#define NCB 8
#define KSZ 2048
#define BATCH 16
#define TOK 2048
#define NTOK (BATCH * TOK)            // 32768
#define NELEM (BATCH * DIM * TOK)     // 4194304
#define T_TILE 128                    // tokens per block
#define NTHR 512                      // 8 waves
#define CHUNK 64
#define NCHUNK (KSZ / CHUNK)          // 32

typedef float f32x4 __attribute__((ext_vector_type(4)));
typedef short s16x8 __attribute__((ext_vector_type(8)));

__device__ __forceinline__ unsigned short f2bf(float f) {
    unsigned u = __float_as_uint(f);
    u = (u + 0x7FFFu + ((u >> 16) & 1u)) >> 16;   // RNE, finite inputs only
    return (unsigned short)u;
}
__device__ __forceinline__ float bf2f(unsigned short h) {
    return __uint_as_float(((unsigned)h) << 16);
}

// ---------------------------------------------------------------------------
// prep: codebooks -> bf16 hi plane only (lh pass needs only B_hi)
// ---------------------------------------------------------------------------
__global__ void rvq_prep_hi(const float* __restrict__ cbs,
                            unsigned short* __restrict__ ch) {
    int i = blockIdx.x * 256 + threadIdx.x;
    ch[i] = f2bf(cbs[i]);
}

// ---------------------------------------------------------------------------
// exact fp32 cnorm + zero loss accumulator
// ---------------------------------------------------------------------------
__global__ void rvq_cnorm(const float* __restrict__ cbs,
                          float* __restrict__ cnorm,
                          float* __restrict__ loss_acc) {
    if (blockIdx.x == 0 && threadIdx.x == 0) *loss_acc = 0.0f;
    int k = blockIdx.x * 256 + threadIdx.x;
    const float4* row = (const float4*)(cbs + (size_t)k * DIM);
    float s = 0.0f;
#pragma unroll
    for (int i = 0; i < DIM / 4; ++i) {
        float4 v = row[i];
        s += v.x * v.x + v.y * v.y + v.z * v.z + v.w * v.w;
    }
    cnorm[k] = s;
}

// ---------------------------------------------------------------------------
// fused RVQ, 8 waves/block (2/SIMD). Approx scores: 2-pass split-bf16 MFMA
// (hh + lh = r * c_hi, err ~2e-3); per-lane min4-over-nt + running top-2;
// exact fp32 rescore of global top-4. Residual LDS-resident across stages.
// ---------------------------------------------------------------------------
__global__ __launch_bounds__(NTHR, 2) void rvq_fused(
        const float* __restrict__ x,            // (B, D, T)
        const float* __restrict__ cbs,          // (NCB, KSZ, DIM) fp32
        const unsigned short* __restrict__ ch,  // bf16 hi
        const float* __restrict__ cng,          // (NCB*KSZ) exact cnorm
        float* __restrict__ out,                // (B, D, T)
        float* __restrict__ codes,              // (B, NCB, T) as float
        float* __restrict__ loss_acc) {
    __shared__ float res_lds[T_TILE][DIM + 4];     // 67584 B
    __shared__ unsigned short Bbuf[2][8192];       // 2 x 16 KB (hi only)
    __shared__ float mv1[T_TILE * 16];             // 8 KB
    __shared__ int   mi1[T_TILE * 16];             // 8 KB
    __shared__ float mv2[T_TILE * 16];             // 8 KB
    __shared__ int   mi2[T_TILE * 16];             // 8 KB
    __shared__ int   best4s[T_TILE][4];            // 2 KB   => ~135 KB total

    const int tid   = threadIdx.x;
    const int lane  = tid & 63;
    const int wv    = __builtin_amdgcn_readfirstlane(tid >> 6);  // 0..7
    const int col16 = lane & 15;
    const int quad  = lane >> 4;

    const int token0 = blockIdx.x * T_TILE;
    const int b      = token0 >> 11;
    const int t_in_b = token0 & (TOK - 1);

    // ---- init: x[b][d][t0..] -> res_lds[t][d] ----
    {
        const float* xb = x + (size_t)b * DIM * TOK + t_in_b;
#pragma unroll
        for (int it = 0; it < 8; ++it) {
            int idx = it * NTHR + tid;           // 0..4095
            int d  = idx >> 5;
            int t4 = (idx & 31) * 4;
            float4 v = *(const float4*)(xb + (size_t)d * TOK + t4);
            res_lds[t4 + 0][d] = v.x;
            res_lds[t4 + 1][d] = v.y;
            res_lds[t4 + 2][d] = v.z;
            res_lds[t4 + 3][d] = v.w;
        }
    }
    __syncthreads();

    float my_loss = 0.0f;

// staging: wave wv owns frags f = wv*2, wv*2+1 (f = nt*4+dc)
#define STAGE_PREFETCH(cc)                                                     \
    {                                                                          \
        int _f0 = wv * 2, _f1 = wv * 2 + 1;                                    \
        stg0 = *(const s16x8*)(ch_s +                                          \
            ((size_t)((cc) * CHUNK + (_f0 >> 2) * 16 + col16)) * DIM +         \
            ((_f0 & 3) * 32 + quad * 8));                                      \
        stg1 = *(const s16x8*)(ch_s +                                          \
            ((size_t)((cc) * CHUNK + (_f1 >> 2) * 16 + col16)) * DIM +         \
            ((_f1 & 3) * 32 + quad * 8));                                      \
    }

#define STAGE_WRITE(buf)                                                       \
    {                                                                          \
        *(s16x8*)&Bbuf[buf][(wv * 2) * 512 + lane * 8]     = stg0;             \
        *(s16x8*)&Bbuf[buf][(wv * 2 + 1) * 512 + lane * 8] = stg1;             \
    }

#define COMPUTE(accv, buf)                                                     \
    {                                                                          \
        _Pragma("unroll")                                                      \
        for (int nt = 0; nt < 4; ++nt) accv[nt] = (f32x4){0.f, 0.f, 0.f, 0.f}; \
        _Pragma("unroll")                                                      \
        for (int dc = 0; dc < 4; ++dc) {                                       \
            s16x8 bh0 = *(const s16x8*)&Bbuf[buf][(0 + dc) * 512 + lane * 8];  \
            s16x8 bh1 = *(const s16x8*)&Bbuf[buf][(4 + dc) * 512 + lane * 8];  \
            s16x8 bh2 = *(const s16x8*)&Bbuf[buf][(8 + dc) * 512 + lane * 8];  \
            s16x8 bh3 = *(const s16x8*)&Bbuf[buf][(12 + dc) * 512 + lane * 8]; \
            accv[0] = __builtin_amdgcn_mfma_f32_16x16x32_bf16(ah[dc], bh0, accv[0], 0, 0, 0); \
            accv[1] = __builtin_amdgcn_mfma_f32_16x16x32_bf16(ah[dc], bh1, accv[1], 0, 0, 0); \
            accv[2] = __builtin_amdgcn_mfma_f32_16x16x32_bf16(ah[dc], bh2, accv[2], 0, 0, 0); \
            accv[3] = __builtin_amdgcn_mfma_f32_16x16x32_bf16(ah[dc], bh3, accv[3], 0, 0, 0); \
            accv[0] = __builtin_amdgcn_mfma_f32_16x16x32_bf16(al[dc], bh0, accv[0], 0, 0, 0); \
            accv[1] = __builtin_amdgcn_mfma_f32_16x16x32_bf16(al[dc], bh1, accv[1], 0, 0, 0); \
            accv[2] = __builtin_amdgcn_mfma_f32_16x16x32_bf16(al[dc], bh2, accv[2], 0, 0, 0); \
            accv[3] = __builtin_amdgcn_mfma_f32_16x16x32_bf16(al[dc], bh3, accv[3], 0, 0, 0); \
        }                                                                      \
    }

// fold chunk cc's scores (approx score = cnorm - 2*dot; rn constant/token)
#define FOLD(accv, cc)                                                         \
    {                                                                          \
        int _ib0 = (cc) * CHUNK + col16;                                       \
        float _cn0 = cn_s[_ib0], _cn1 = cn_s[_ib0 + 16];                       \
        float _cn2 = cn_s[_ib0 + 32], _cn3 = cn_s[_ib0 + 48];                  \
        _Pragma("unroll")                                                      \
        for (int r = 0; r < 4; ++r) {                                          \
            float p0 = fmaf(-2.0f, accv[0][r], _cn0);                          \
            float p1 = fmaf(-2.0f, accv[1][r], _cn1);                          \
            float p2 = fmaf(-2.0f, accv[2][r], _cn2);                          \
            float p3 = fmaf(-2.0f, accv[3][r], _cn3);                          \
            bool c01 = p1 < p0;                                                \
            float m01 = c01 ? p1 : p0; int j01 = c01 ? _ib0 + 16 : _ib0;       \
            bool c23 = p3 < p2;                                                \
            float m23 = c23 ? p3 : p2; int j23 = c23 ? _ib0 + 48 : _ib0 + 32;  \
            bool cf = m23 < m01;                                               \
            float m = cf ? m23 : m01; int jm = cf ? j23 : j01;                 \
            bool b1 = m < v1[r];                                               \
            bool b2 = m < v2[r];                                               \
            v2[r] = b1 ? v1[r] : (b2 ? m : v2[r]);                             \
            i2[r] = b1 ? i1[r] : (b2 ? jm : i2[r]);                            \
            v1[r] = b1 ? m : v1[r];                                            \
            i1[r] = b1 ? jm : i1[r];                                           \
        }                                                                      \
    }

#pragma unroll 1
    for (int s = 0; s < NCB; ++s) {
        const unsigned short* __restrict__ ch_s = ch  + (size_t)s * KSZ * DIM;
        const float* __restrict__ cb_s = cbs + (size_t)s * KSZ * DIM;
        const float* __restrict__ cn_s = cng + (size_t)s * KSZ;

        // ---- A fragments (hi+lo) from LDS residual; wave owns 16 tokens ----
        s16x8 ah[4], al[4];
#pragma unroll
        for (int dc = 0; dc < 4; ++dc) {
            int t  = wv * 16 + col16;
            int d0 = dc * 32 + quad * 8;
            float4 u = *(const float4*)&res_lds[t][d0];
            float4 w = *(const float4*)&res_lds[t][d0 + 4];
            float e[8] = {u.x, u.y, u.z, u.w, w.x, w.y, w.z, w.w};
            s16x8 hv, lv;
#pragma unroll
            for (int j = 0; j < 8; ++j) {
                unsigned short h = f2bf(e[j]);
                hv[j] = (short)h;
                lv[j] = (short)f2bf(e[j] - bf2f(h));
            }
            ah[dc] = hv;
            al[dc] = lv;
        }

        float v1[4], v2[4]; int i1[4], i2[4];
#pragma unroll
        for (int r = 0; r < 4; ++r) {
            v1[r] = 3.4e38f; v2[r] = 3.4e38f; i1[r] = 0; i2[r] = 0;
        }

        s16x8 stg0, stg1;
        f32x4 accA[4], accB[4];

        // ---- pipelined chunk sweep ----
        STAGE_PREFETCH(0); STAGE_WRITE(0); __syncthreads();
        STAGE_PREFETCH(1);
        COMPUTE(accA, 0);
        STAGE_WRITE(1); __syncthreads();
#pragma unroll 1
        for (int c = 1; c < 31; c += 2) {
            STAGE_PREFETCH(c + 1);
            COMPUTE(accB, 1);
            FOLD(accA, c - 1);
            STAGE_WRITE(0);
            __syncthreads();
            STAGE_PREFETCH(c + 2);
            COMPUTE(accA, 0);
            FOLD(accB, c);
            STAGE_WRITE(1);
            __syncthreads();
        }
        COMPUTE(accB, 1);
        FOLD(accA, 30);
        FOLD(accB, 31);

        // ---- publish per-lane top-2 ----
#pragma unroll
        for (int r = 0; r < 4; ++r) {
            int t = wv * 16 + quad * 4 + r;
            mv1[t * 16 + col16] = v1[r];
            mi1[t * 16 + col16] = i1[r];
            mv2[t * 16 + col16] = v2[r];
            mi2[t * 16 + col16] = i2[r];
        }
        __syncthreads();

        // ---- merge 32 candidates -> top-4 per token ----
        if (tid < T_TILE) {
            const int t = tid;
            float bv[4] = {3.4e38f, 3.4e38f, 3.4e38f, 3.4e38f};
            int   bi[4] = {0x7FFFFFFF, 0x7FFFFFFF, 0x7FFFFFFF, 0x7FFFFFFF};
#pragma unroll
            for (int col = 0; col < 16; ++col) {
#pragma unroll
                for (int w = 0; w < 2; ++w) {
                    float v = w ? mv2[t * 16 + col] : mv1[t * 16 + col];
                    int   i = w ? mi2[t * 16 + col] : mi1[t * 16 + col];
#pragma unroll
                    for (int j = 0; j < 4; ++j) {
                        if (v < bv[j] || (v == bv[j] && i < bi[j])) {
                            float tv = bv[j]; bv[j] = v; v = tv;
                            int   ti = bi[j]; bi[j] = i; i = ti;
                        }
                    }
                }
            }
#pragma unroll
            for (int j = 0; j < 4; ++j) best4s[t][j] = bi[j];
        }
        __syncthreads();

        // ---- exact fp32 rescore: 4 threads per token, 1 candidate each ----
        {
            const int t  = tid >> 2;
            const int cs = tid & 3;
            const int cand = best4s[t][cs];
            const float* crow = cb_s + (size_t)cand * DIM;
            float n0 = 0, n1 = 0, n2 = 0, n3 = 0;
            float a0 = 0, a1 = 0, a2 = 0, a3 = 0;
#pragma unroll 8
            for (int d4 = 0; d4 < DIM / 4; ++d4) {
                float4 r4 = *(const float4*)&res_lds[t][d4 * 4];
                float4 q4 = *(const float4*)&crow[d4 * 4];
                n0 = fmaf(r4.x, r4.x, n0); n1 = fmaf(r4.y, r4.y, n1);
                n2 = fmaf(r4.z, r4.z, n2); n3 = fmaf(r4.w, r4.w, n3);
                a0 = fmaf(r4.x, q4.x, a0); a1 = fmaf(r4.y, q4.y, a1);
                a2 = fmaf(r4.z, q4.z, a2); a3 = fmaf(r4.w, q4.w, a3);
            }
            float rn  = (n0 + n1) + (n2 + n3);
            float dot = (a0 + a1) + (a2 + a3);
            float dist = fmaf(-2.0f, dot, rn) + cn_s[cand];
            int best = cand;
#pragma unroll
            for (int mk = 1; mk <= 2; mk <<= 1) {
                float od = __shfl_xor(dist, mk, 64);
                int   oi = __shfl_xor(best, mk, 64);
                if (od < dist || (od == dist && oi < best)) {
                    dist = od; best = oi;
                }
            }
            if (cs == 0)
                codes[(size_t)b * (NCB * TOK) + (size_t)s * TOK + t_in_b + t] =
                    (float)best;
            // update my 32-dim slice of the token's residual + loss partial
            const float* qrow = cb_s + (size_t)best * DIM;
            float lp = 0.0f;
#pragma unroll
            for (int d4 = 0; d4 < 8; ++d4) {
                int d = cs * 32 + d4 * 4;
                float4 r4 = *(const float4*)&res_lds[t][d];
                float4 q4 = *(const float4*)&qrow[d];
                float4 nr;
                nr.x = r4.x - q4.x; nr.y = r4.y - q4.y;
                nr.z = r4.z - q4.z; nr.w = r4.w - q4.w;
                *(float4*)&res_lds[t][d] = nr;
                lp += nr.x * nr.x + nr.y * nr.y + nr.z * nr.z + nr.w * nr.w;
            }
            my_loss += lp;
        }
        __syncthreads();
    }

    // ---- epilogue: out[b][d][t] = x - residual ----
    {
        const float* xb = x + (size_t)b * DIM * TOK + t_in_b;
        float* ob = out + (size_t)b * DIM * TOK + t_in_b;
#pragma unroll
        for (int it = 0; it < 8; ++it) {
            int idx = it * NTHR + tid;
            int d  = idx >> 5;
            int t4 = (idx & 31) * 4;
            float4 v = *(const float4*)(xb + (size_t)d * TOK + t4);
            float4 o;
            o.x = v.x - res_lds[t4 + 0][d];
            o.y = v.y - res_lds[t4 + 1][d];
            o.z = v.z - res_lds[t4 + 2][d];
            o.w = v.w - res_lds[t4 + 3][d];
            *(float4*)(ob + (size_t)d * TOK + t4) = o;
        }
    }

    // ---- loss reduction ----
#pragma unroll
    for (int off = 32; off > 0; off >>= 1)
        my_loss += __shfl_down(my_loss, off, 64);
    if (lane == 0) atomicAdd(loss_acc, my_loss);
}

// ---------------------------------------------------------------------------
__global__ void rvq_loss_fin(const float* __restrict__ loss_acc,
                             float* __restrict__ loss_out) {
    *loss_out = *loss_acc * (1.0f / (float)NELEM);
}

// ---------------------------------------------------------------------------
extern "C" void kernel_launch(void* const* d_in, const int* in_sizes, int n_in,
                              void* d_out, int out_size, void* d_ws, size_t ws_size,
                              hipStream_t stream) {
    const float* x   = (const float*)d_in[0];   // (B, D, T)
    const float* cbs = (const float*)d_in[1];   // (NCB, KSZ, DIM)

    float* out      = (float*)d_out;
    float* codes    = out + NELEM;
    float* loss_out = out + NELEM + (size_t)BATCH * NCB * TOK;

    float* wsf      = (float*)d_ws;
    float* loss_acc = wsf;
    unsigned short* ch = (unsigned short*)(wsf + 256);
    float* cng = (float*)(ch + (size_t)NCB * KSZ * DIM);

    hipLaunchKernelGGL(rvq_prep_hi, dim3((NCB * KSZ * DIM) / 256), dim3(256),
                       0, stream, cbs, ch);
    hipLaunchKernelGGL(rvq_cnorm, dim3((NCB * KSZ) / 256), dim3(256), 0, stream,
                       cbs, cng, loss_acc);
    hipLaunchKernelGGL(rvq_fused, dim3(NTOK / T_TILE), dim3(NTHR), 0, stream,
                       x, cbs, ch, cng, out, codes, loss_acc);
    hipLaunchKernelGGL(rvq_loss_fin, dim3(1), dim3(1), 0, stream,
                       loss_acc, loss_out);
}